// Round 1
// baseline (137.573 us; speedup 1.0000x reference)
//
#include <hip/hip_runtime.h>
#include <hip/hip_bf16.h>

#define LSEQ 20000
#define DEG  16
#define F    128
#define ALPHA 0.2f

typedef __bf16 bf16x8 __attribute__((ext_vector_type(8)));
typedef float  f32x4  __attribute__((ext_vector_type(4)));

__device__ __forceinline__ float bf_lo(unsigned int u) { return __uint_as_float(u << 16); }
__device__ __forceinline__ float bf_hi(unsigned int u) { return __uint_as_float(u & 0xffff0000u); }
__device__ __forceinline__ float elu_f(float v) { return v > 0.f ? v : __expf(v) - 1.f; }

// Prep: wt[n*F+k] = bf16(W[k*F+n]) (32 KB) and wa[k] = (W@a1)[k],
// wa[F+k] = (W@a2)[k] (fp32, for the s1/s2 path).
__global__ __launch_bounds__(256) void gat_wt(const float* __restrict__ W,
                                              const float* __restrict__ a,
                                              __hip_bfloat16* __restrict__ wt,
                                              float* __restrict__ wa)
{
    const int t = blockIdx.x * 256 + threadIdx.x;
    for (int i = t; i < F * F; i += 16 * 256) {
        const int k = i >> 7, n = i & (F - 1);
        wt[n * F + k] = __float2bfloat16(W[i]);
    }
    if (blockIdx.x == 0 && threadIdx.x < F) {
        const int k = threadIdx.x;
        float acc1 = 0.f, acc2 = 0.f;
        for (int n = 0; n < F; ++n) {
            const float w = W[k * F + n];
            acc1 = fmaf(w, a[n],     acc1);
            acc2 = fmaf(w, a[F + n], acc2);
        }
        wa[k]     = acc1;
        wa[F + k] = acc2;
    }
}

// MFMA gemm. R9: LDS pad replaced by 16B-chunk XOR swizzle (phys chunk =
// chunk ^ (row&7)) -> LDS exactly 32 KB -> 5 blocks/CU (launch_bounds 256,5)
// -> all 1250 blocks co-resident, no straggler round. Bank groups stay
// balanced: (4kt+q)^(m&7) hits each of the 8 4-bank groups exactly 8x per
// ds_read_b128. row&7 == m&7 (ct*16 is 0 mod 8) so the XOR hoists out of
// the ct loop.
// D-layout: lane (q=lane>>4, m=lane&15) holds y[i0+m][ct*16+q*4+r] ->
// contiguous 8B stores. s1/s2 from fp32 x against wa1/wa2.
__global__ __launch_bounds__(256, 5) void gat_gemm(const float* __restrict__ x,
                                                   const __hip_bfloat16* __restrict__ wt,
                                                   const float* __restrict__ wa,
                                                   __hip_bfloat16* __restrict__ y16,
                                                   float* __restrict__ s1,
                                                   float* __restrict__ s2)
{
    __shared__ __hip_bfloat16 wl[F][F];   // 32 KB exactly

    const int t    = threadIdx.x;
    const int lane = t & 63;
    const int wid  = t >> 6;
    const int i0   = (blockIdx.x * 4 + wid) * 16;   // 16 x-rows per wave
    const int m    = lane & 15;
    const int q    = lane >> 4;

    // Stage wt -> LDS: 2048 uint4, 8 per thread, coalesced; swizzled dest.
    {
        const uint4* wg = reinterpret_cast<const uint4*>(wt);
        #pragma unroll
        for (int i = 0; i < 8; ++i) {
            const int g   = t + 256 * i;       // global uint4 index
            const int row = g >> 4;            // 16 uint4 per row
            const int c8  = g & 15;            // logical 8-half chunk
            *reinterpret_cast<uint4*>(&wl[row][((c8 ^ (row & 7)) * 8)]) = wg[g];
        }
    }

    // fp32 x chunks: lane holds x[i0+m][q*8 + kt*32 + j], j=0..7, kt=0..3.
    const float* xr = x + (size_t)(i0 + m) * F + q * 8;
    float4 xf[8];
    #pragma unroll
    for (int kt = 0; kt < 4; ++kt) {
        xf[2*kt]   = *reinterpret_cast<const float4*>(xr + kt * 32);
        xf[2*kt+1] = *reinterpret_cast<const float4*>(xr + kt * 32 + 4);
    }

    // s1/s2: fp32 dot with wa1/wa2 over this lane's 32 k's, reduce over q.
    float p1 = 0.f, p2 = 0.f;
    {
        const float* w1p = wa + q * 8;
        const float* w2p = wa + F + q * 8;
        #pragma unroll
        for (int kt = 0; kt < 4; ++kt) {
            const float4 u0 = *reinterpret_cast<const float4*>(w1p + kt * 32);
            const float4 u1 = *reinterpret_cast<const float4*>(w1p + kt * 32 + 4);
            const float4 v0 = *reinterpret_cast<const float4*>(w2p + kt * 32);
            const float4 v1 = *reinterpret_cast<const float4*>(w2p + kt * 32 + 4);
            const float4 xa = xf[2*kt], xb = xf[2*kt+1];
            p1 = fmaf(xa.x,u0.x,p1); p1 = fmaf(xa.y,u0.y,p1);
            p1 = fmaf(xa.z,u0.z,p1); p1 = fmaf(xa.w,u0.w,p1);
            p1 = fmaf(xb.x,u1.x,p1); p1 = fmaf(xb.y,u1.y,p1);
            p1 = fmaf(xb.z,u1.z,p1); p1 = fmaf(xb.w,u1.w,p1);
            p2 = fmaf(xa.x,v0.x,p2); p2 = fmaf(xa.y,v0.y,p2);
            p2 = fmaf(xa.z,v0.z,p2); p2 = fmaf(xa.w,v0.w,p2);
            p2 = fmaf(xb.x,v1.x,p2); p2 = fmaf(xb.y,v1.y,p2);
            p2 = fmaf(xb.z,v1.z,p2); p2 = fmaf(xb.w,v1.w,p2);
        }
    }
    p1 += __shfl_xor(p1, 16); p1 += __shfl_xor(p1, 32);
    p2 += __shfl_xor(p2, 16); p2 += __shfl_xor(p2, 32);
    if (lane < 16) {
        s1[i0 + m] = p1;
        s2[i0 + m] = p2;
    }

    // B-fragments (x^T): B[k=q*8+j][n=m] = x[i0+m][k].
    bf16x8 bfr[4];
    #pragma unroll
    for (int kt = 0; kt < 4; ++kt) {
        const float4 qa = xf[2*kt], qb = xf[2*kt+1];
        bf16x8 f;
        f[0] = (__bf16)qa.x; f[1] = (__bf16)qa.y; f[2] = (__bf16)qa.z; f[3] = (__bf16)qa.w;
        f[4] = (__bf16)qb.x; f[5] = (__bf16)qb.y; f[6] = (__bf16)qb.z; f[7] = (__bf16)qb.w;
        bfr[kt] = f;
    }

    __syncthreads();   // wt staging complete

    // ct loop over 8 column tiles; A-frag from LDS: A[mm=m][k=q*8+j].
    #pragma unroll
    for (int ct = 0; ct < 8; ++ct) {
        union { uint4 u; bf16x8 v; } afr[4];
        const int row = ct * 16 + m;
        #pragma unroll
        for (int kt = 0; kt < 4; ++kt)
            afr[kt].u = *reinterpret_cast<const uint4*>(
                            &wl[row][(((kt * 4 + q) ^ (m & 7)) * 8)]);

        f32x4 acc = {0.f, 0.f, 0.f, 0.f};
        #pragma unroll
        for (int kt = 0; kt < 4; ++kt)
            acc = __builtin_amdgcn_mfma_f32_16x16x32_bf16(afr[kt].v, bfr[kt], acc, 0, 0, 0);

        union { uint2 u; __hip_bfloat162 h[2]; } pk;
        pk.h[0] = __float22bfloat162_rn(make_float2(acc[0], acc[1]));
        pk.h[1] = __float22bfloat162_rn(make_float2(acc[2], acc[3]));
        *reinterpret_cast<uint2*>(y16 + (size_t)(i0 + m) * F + ct * 16 + q * 4) = pk.u;
    }
}

// Kernel 2, R9 rewrite: lane (g=lane>>4, d=lane&15) owns output features
// [d*8, d*8+8) of node g0+g. Softmax phase unchanged (lane = node*16 + d).
// Gather phase: per neighbor slot k, ds_bpermute broadcasts group g's k-th
// row index / attn weight to all 16 lanes of the group; one VGPR-addressed
// global_load_dwordx4 then fetches 4 rows (one per group) per instruction.
// VMEM per wave: 68 -> 21; VALU roughly halved; accumulation order per
// feature identical to R8 (bit-exact output). XCD-pair <-> batch pinning
// keeps the 5.1MB y16 window resident per 8MB L2 pair.
__global__ __launch_bounds__(256, 4) void gat_attn(const int* __restrict__ adj,
                                                   const __hip_bfloat16* __restrict__ y16,
                                                   const float* __restrict__ s1,
                                                   const float* __restrict__ s2,
                                                   float* __restrict__ out)
{
    const int lane  = threadIdx.x & 63;
    const int wid   = threadIdx.x >> 6;
    const int x8    = blockIdx.x & 7;
    const int j     = blockIdx.x >> 3;          // 0..624
    const int batch = x8 >> 1;                  // XCD pair -> batch
    const int grp   = j * 2 + (x8 & 1);         // 0..1249 (16-node group)
    const int base  = batch * LSEQ;
    const int g0    = base + grp * 16 + wid * 4;   // this wave's first node
    const int d     = lane & 15;
    const int g16   = lane & 48;                // group base lane

    // adj for 4 nodes: 64 contiguous ints, fully coalesced.
    const int av = adj[(size_t)g0 * DEG + lane];

    const float sv = s1[base + av];
    // s2 term: head lane (d==0) of each 16-group loads, then broadcast.
    float s2l = (d == 0) ? s2[base + av] : 0.f;
    const float s2v = __shfl(s2l, g16);
    const float e = sv + s2v;
    const float t = e > 0.f ? e : ALPHA * e;

    // softmax within each 16-lane group (xor offsets stay in-group).
    float mx = t;
    #pragma unroll
    for (int off = 1; off < 16; off <<= 1) mx = fmaxf(mx, __shfl_xor(mx, off));
    const float w = __expf(t - mx);
    float p = w;
    #pragma unroll
    for (int off = 1; off < 16; off <<= 1) p += __shfl_xor(p, off);
    const float attn = w / p;

    // Gather: 16B per lane per neighbor row; 4 rows per load instruction.
    const char* yb = reinterpret_cast<const char*>(y16 + ((size_t)base << 7)) + d * 16;
    float acc[8] = {0.f, 0.f, 0.f, 0.f, 0.f, 0.f, 0.f, 0.f};

    uint4 va[8], vb[8];
    #pragma unroll
    for (int k = 0; k < 8; ++k) {
        const int r = __shfl(av, g16 + k);
        va[k] = *reinterpret_cast<const uint4*>(yb + ((size_t)r << 8));
    }
    #pragma unroll
    for (int k = 0; k < 8; ++k) {
        const int r = __shfl(av, g16 + 8 + k);
        vb[k] = *reinterpret_cast<const uint4*>(yb + ((size_t)r << 8));
    }

    #pragma unroll
    for (int k = 0; k < 8; ++k) {
        const float wk = __shfl(attn, g16 + k);
        const uint4 v = va[k];
        acc[0] = fmaf(wk, bf_lo(v.x), acc[0]);
        acc[1] = fmaf(wk, bf_hi(v.x), acc[1]);
        acc[2] = fmaf(wk, bf_lo(v.y), acc[2]);
        acc[3] = fmaf(wk, bf_hi(v.y), acc[3]);
        acc[4] = fmaf(wk, bf_lo(v.z), acc[4]);
        acc[5] = fmaf(wk, bf_hi(v.z), acc[5]);
        acc[6] = fmaf(wk, bf_lo(v.w), acc[6]);
        acc[7] = fmaf(wk, bf_hi(v.w), acc[7]);
    }
    #pragma unroll
    for (int k = 0; k < 8; ++k) {
        const float wk = __shfl(attn, g16 + 8 + k);
        const uint4 v = vb[k];
        acc[0] = fmaf(wk, bf_lo(v.x), acc[0]);
        acc[1] = fmaf(wk, bf_hi(v.x), acc[1]);
        acc[2] = fmaf(wk, bf_lo(v.y), acc[2]);
        acc[3] = fmaf(wk, bf_hi(v.y), acc[3]);
        acc[4] = fmaf(wk, bf_lo(v.z), acc[4]);
        acc[5] = fmaf(wk, bf_hi(v.z), acc[5]);
        acc[6] = fmaf(wk, bf_lo(v.w), acc[6]);
        acc[7] = fmaf(wk, bf_hi(v.w), acc[7]);
    }

    // ELU + store: node g0+g, features [d*8, d*8+8) -> 512B/row contiguous.
    float* op = out + (size_t)(g0 + (lane >> 4)) * F + d * 8;
    const float4 o0 = make_float4(elu_f(acc[0]), elu_f(acc[1]),
                                  elu_f(acc[2]), elu_f(acc[3]));
    const float4 o1 = make_float4(elu_f(acc[4]), elu_f(acc[5]),
                                  elu_f(acc[6]), elu_f(acc[7]));
    *reinterpret_cast<float4*>(op)     = o0;
    *reinterpret_cast<float4*>(op + 4) = o1;
}

extern "C" void kernel_launch(void* const* d_in, const int* in_sizes, int n_in,
                              void* d_out, int out_size, void* d_ws, size_t ws_size,
                              hipStream_t stream) {
    const float* x   = (const float*)d_in[0];
    const int*   adj = (const int*)d_in[1];
    const float* W   = (const float*)d_in[2];
    const float* a   = (const float*)d_in[3];
    float* out = (float*)d_out;

    const int BL = in_sizes[0] / F;   // bs*L = 80000

    __hip_bfloat16* y16 = (__hip_bfloat16*)d_ws;
    float* s1 = (float*)((char*)d_ws + (size_t)BL * F * sizeof(__hip_bfloat16));
    float* s2 = s1 + BL;
    __hip_bfloat16* wt = (__hip_bfloat16*)(s2 + BL);
    float* wa = (float*)(wt + F * F);

    gat_wt  <<<16, 256, 0, stream>>>(W, a, wt, wa);
    gat_gemm<<<BL / 64, 256, 0, stream>>>(x, wt, wa, y16, s1, s2);
    gat_attn<<<BL / 16, 256, 0, stream>>>(adj, y16, s1, s2, out);
}